// Round 2
// baseline (521.330 us; speedup 1.0000x reference)
//
#include <hip/hip_runtime.h>

// out[b, f, i, j] = relu(w0[f]*t[b,i] + w1[f]*t[b,j] + w2[f])
// t: (BSZ, SZ) f32, w: (1, NF, 3, 1) f32, out: (BSZ, NF, SZ*SZ) f32
// Pure write-BW-bound: 512 MiB out, ~32 KB in.

#define BSZ 16
#define SZ  512
#define NF  32

constexpr int ROWS_PER_BLOCK = 64;
constexpr int CHUNKS = SZ / ROWS_PER_BLOCK;   // 8
constexpr int BLOCK  = 256;

typedef float vfloat4 __attribute__((ext_vector_type(4)));

__global__ __launch_bounds__(BLOCK) void pairwise_kernel(
    const float* __restrict__ t, const float* __restrict__ w,
    float* __restrict__ out)
{
    __shared__ float tj[SZ];                // w1[f] * t[b, :]
    __shared__ float ai[ROWS_PER_BLOCK];    // w0[f] * t[b, row0+r] + w2[f]

    const int blk   = blockIdx.x;           // b*(NF*CHUNKS) + f*CHUNKS + chunk
    const int chunk = blk & (CHUNKS - 1);
    const int f     = (blk >> 3) & (NF - 1);
    const int b     = blk >> 8;             // 3 + 5 bits

    const float w0 = w[f * 3 + 0];
    const float w1 = w[f * 3 + 1];
    const float w2 = w[f * 3 + 2];

    const float* tb = t + b * SZ;
    const int row0 = chunk * ROWS_PER_BLOCK;

    // Stage scaled row vector and per-row affine terms into LDS.
    for (int idx = threadIdx.x; idx < SZ; idx += BLOCK)
        tj[idx] = w1 * tb[idx];
    for (int idx = threadIdx.x; idx < ROWS_PER_BLOCK; idx += BLOCK)
        ai[idx] = w0 * tb[row0 + idx] + w2;
    __syncthreads();

    float* outbase = out + ((size_t)(b * NF + f) * SZ + row0) * SZ;

    const int col4 = threadIdx.x & 127;     // 0..127 -> column group of 4
    const int rsub = threadIdx.x >> 7;      // 0..1
    const vfloat4 c = ((const vfloat4*)tj)[col4];   // loop-invariant per thread

    for (int r = rsub; r < ROWS_PER_BLOCK; r += 2) {
        const float a = ai[r];              // wave-wide broadcast read
        vfloat4 o;
        o.x = fmaxf(a + c.x, 0.0f);
        o.y = fmaxf(a + c.y, 0.0f);
        o.z = fmaxf(a + c.z, 0.0f);
        o.w = fmaxf(a + c.w, 0.0f);
        __builtin_nontemporal_store(o, (vfloat4*)(outbase + (size_t)r * SZ) + col4);
    }
}

extern "C" void kernel_launch(void* const* d_in, const int* in_sizes, int n_in,
                              void* d_out, int out_size, void* d_ws, size_t ws_size,
                              hipStream_t stream) {
    const float* t = (const float*)d_in[0];
    const float* w = (const float*)d_in[1];
    float* out = (float*)d_out;

    const int grid = BSZ * NF * CHUNKS;     // 4096 blocks
    pairwise_kernel<<<dim3(grid), dim3(BLOCK), 0, stream>>>(t, w, out);
}

// Round 3
// 520.060 us; speedup vs baseline: 1.0024x; 1.0024x over previous
//
#include <hip/hip_runtime.h>

// out[b, f, i, j] = relu(w0[f]*t[b,i] + w1[f]*t[b,j] + w2[f])
// t: (BSZ, SZ) f32, w: (1, NF, 3, 1) f32, out: (BSZ, NF, SZ*SZ) f32
// Pure write-BW-bound: 512 MiB out, ~32 KB in. Floor ~85 us @ 6.3 TB/s.
// R2 post-mortem: NT stores measured ~3.0 TB/s vs 6.26 TB/s for the
// harness fill kernel with plain stores -> drop the nt flag.

#define BSZ 16
#define SZ  512
#define NF  32

constexpr int ROWS_PER_BLOCK = 64;
constexpr int CHUNKS = SZ / ROWS_PER_BLOCK;   // 8
constexpr int BLOCK  = 256;

typedef float vfloat4 __attribute__((ext_vector_type(4)));

__global__ __launch_bounds__(BLOCK) void pairwise_kernel(
    const float* __restrict__ t, const float* __restrict__ w,
    float* __restrict__ out)
{
    __shared__ float tj[SZ];                // w1[f] * t[b, :]
    __shared__ float ai[ROWS_PER_BLOCK];    // w0[f] * t[b, row0+r] + w2[f]

    const int blk   = blockIdx.x;           // b*(NF*CHUNKS) + f*CHUNKS + chunk
    const int chunk = blk & (CHUNKS - 1);
    const int f     = (blk >> 3) & (NF - 1);
    const int b     = blk >> 8;             // 3 + 5 bits

    const float w0 = w[f * 3 + 0];
    const float w1 = w[f * 3 + 1];
    const float w2 = w[f * 3 + 2];

    const float* tb = t + b * SZ;
    const int row0 = chunk * ROWS_PER_BLOCK;

    // Stage scaled row vector and per-row affine terms into LDS.
    for (int idx = threadIdx.x; idx < SZ; idx += BLOCK)
        tj[idx] = w1 * tb[idx];
    for (int idx = threadIdx.x; idx < ROWS_PER_BLOCK; idx += BLOCK)
        ai[idx] = w0 * tb[row0 + idx] + w2;
    __syncthreads();

    float* outbase = out + ((size_t)(b * NF + f) * SZ + row0) * SZ;

    const int col4 = threadIdx.x & 127;     // 0..127 -> column group of 4
    const int rsub = threadIdx.x >> 7;      // 0..1
    const vfloat4 c = ((const vfloat4*)tj)[col4];   // loop-invariant per thread

    #pragma unroll
    for (int r = rsub; r < ROWS_PER_BLOCK; r += 2) {
        const float a = ai[r];              // wave-wide broadcast read
        vfloat4 o;
        o.x = fmaxf(a + c.x, 0.0f);
        o.y = fmaxf(a + c.y, 0.0f);
        o.z = fmaxf(a + c.z, 0.0f);
        o.w = fmaxf(a + c.w, 0.0f);
        ((vfloat4*)(outbase + (size_t)r * SZ))[col4] = o;   // plain store (no nt)
    }
}

extern "C" void kernel_launch(void* const* d_in, const int* in_sizes, int n_in,
                              void* d_out, int out_size, void* d_ws, size_t ws_size,
                              hipStream_t stream) {
    const float* t = (const float*)d_in[0];
    const float* w = (const float*)d_in[1];
    float* out = (float*)d_out;

    const int grid = BSZ * NF * CHUNKS;     // 4096 blocks
    pairwise_kernel<<<dim3(grid), dim3(BLOCK), 0, stream>>>(t, w, out);
}